// Round 6
// baseline (10158.029 us; speedup 1.0000x reference)
//
#include <hip/hip_runtime.h>
#include <hip/hip_bf16.h>
#include <stdint.h>

#define NB 32
#define NR 2048
#define NC 64
#define NO 64
#define NK 16
#define CHC 8                 // c's per chunk
#define NCHUNK (NC / CHC)     // 8 chunks

__device__ __forceinline__ uint32_t f2bf(float f) {
  uint32_t u = __builtin_bit_cast(uint32_t, f);
  return (u + 0x7fffu + ((u >> 16) & 1u)) >> 16;  // RNE
}
__device__ __forceinline__ uint32_t packbf2(float lo, float hi) {
  return f2bf(lo) | (f2bf(hi) << 16);
}

__device__ __forceinline__ void gload_lds16(const float* g, float* l) {
  __builtin_amdgcn_global_load_lds(
      (const __attribute__((address_space(1))) void*)g,
      (__attribute__((address_space(3))) void*)l, 16, 0, 0);
}

// x[b][r][c] -> xT[r][c][b]
__global__ __launch_bounds__(256) void transpose_x(const float* __restrict__ x,
                                                   float* __restrict__ xT) {
  __shared__ float tile[32][65];
  const int r = blockIdx.x, t = threadIdx.x;
  {
    const int b = t >> 3, c0 = (t & 7) << 3;
    const float* xp = x + ((size_t)b * NR + r) * NC + c0;
    float4 v0 = *(const float4*)xp;
    float4 v1 = *(const float4*)(xp + 4);
    tile[b][c0 + 0] = v0.x; tile[b][c0 + 1] = v0.y; tile[b][c0 + 2] = v0.z; tile[b][c0 + 3] = v0.w;
    tile[b][c0 + 4] = v1.x; tile[b][c0 + 5] = v1.y; tile[b][c0 + 6] = v1.z; tile[b][c0 + 7] = v1.w;
  }
  __syncthreads();
  {
    const int c = t >> 2, b0 = (t & 3) << 3;
    float4 w0 = make_float4(tile[b0 + 0][c], tile[b0 + 1][c], tile[b0 + 2][c], tile[b0 + 3][c]);
    float4 w1 = make_float4(tile[b0 + 4][c], tile[b0 + 5][c], tile[b0 + 6][c], tile[b0 + 7][c]);
    float* op = xT + ((size_t)r * NC + c) * NB + b0;
    *(float4*)op = w0;
    *(float4*)(op + 4) = w1;
  }
}

// R4 structure (best measured): m97-style double-buffered LDS streaming GEMM,
// {stage(t+1); compute(t); __syncthreads()}. NO XCD swizzle (R5 A/B: swizzle
// cost +234MB FETCH / +145us by breaking L3 sharing of xT + W replay residue).
// Only change vs R4: __launch_bounds__(256,6) -> 6 blocks/CU (24KB LDS each,
// VGPR cap 85 >= the 64 this kernel uses), doubling independent streams per
// CU so cross-block TLP hides each block's barrier drain.
__global__ __launch_bounds__(256, 6) void priors_gemm(const float* __restrict__ xT,
                                                      const float* __restrict__ W,
                                                      __hip_bfloat16* __restrict__ priors) {
  __shared__ float ldsW[2][4][CHC][64];  // [buf][r'][c][o]  2 x 8KB
  __shared__ float ldsX[2][4][CHC][32];  // [buf][r'][c][b]  2 x 4KB
  const int w = threadIdx.x >> 6, lane = threadIdx.x & 63;
  const int bg = lane >> 3, og = lane & 7;
  const int k = blockIdx.x & 15;             // 16 k's of one rquad adjacent -> xT/W L3-hot
  const int rbase = (blockIdx.x >> 4) * 4;
  const int r = rbase + w;

  // W staging: instr i covers row rbase + (w>>1) + i*2, cols [c0+(w&1)*4, +4) x 64 o.
  const float* wsrc = W + ((size_t)(k * NR + rbase + (w >> 1))) * (NC * NO)
                        + (w & 1) * 256 + lane * 4;
  // x staging: wave w stages its own row r, [8 c][32 b] contiguous.
  const float* xsrc = xT + ((size_t)r * NC) * NB + lane * 4;

  float acc[4][8] = {};

  auto stage = [&](int t, int buf) {
    const int c0 = t * CHC;
    float* dw = &ldsW[buf][0][0][0] + w * 256;
    gload_lds16(wsrc + c0 * 64, dw);
    gload_lds16(wsrc + (size_t)2 * (NC * NO) + c0 * 64, dw + 1024);
    gload_lds16(xsrc + c0 * 32, &ldsX[buf][0][0][0] + w * 256);
  };

  auto compute = [&](int buf) {
#pragma unroll
    for (int c = 0; c < CHC; ++c) {
      float4 xv = *(const float4*)&ldsX[buf][w][c][bg * 4];
      float4 wa = *(const float4*)&ldsW[buf][w][c][og * 8];
      float4 wb = *(const float4*)&ldsW[buf][w][c][og * 8 + 4];
      float xr[4] = {xv.x, xv.y, xv.z, xv.w};
      float wr[8] = {wa.x, wa.y, wa.z, wa.w, wb.x, wb.y, wb.z, wb.w};
#pragma unroll
      for (int a = 0; a < 4; ++a)
#pragma unroll
        for (int b = 0; b < 8; ++b) acc[a][b] = fmaf(xr[a], wr[b], acc[a][b]);
    }
  };

  stage(0, 0);
  __syncthreads();
#pragma unroll
  for (int t = 0; t < NCHUNK; ++t) {
    if (t + 1 < NCHUNK) stage(t + 1, (t + 1) & 1);  // prefetch next chunk
    compute(t & 1);                                  // ds_read + FMA current
    __syncthreads();                                 // drain prefetch, swap
  }

#pragma unroll
  for (int i = 0; i < 4; ++i) {
    uint4 uv;
    uv.x = packbf2(acc[i][0], acc[i][1]);
    uv.y = packbf2(acc[i][2], acc[i][3]);
    uv.z = packbf2(acc[i][4], acc[i][5]);
    uv.w = packbf2(acc[i][6], acc[i][7]);
    __hip_bfloat16* pp = priors + (((size_t)(k * NB + bg * 4 + i) * NR) + r) * NO + og * 8;
    *(uint4*)pp = uv;
  }
}

// Routing pass. Block per (k,b). Lane: g = lane/8 (r within group-of-8), sl = lane%8 (o-slice of 8).
// PASS==1: phase A computes o0 = squash(mean_r p) in-block (priors read #1);
//          phase B: l = a_r = p.o0, stores a_r, writes o1 (priors read #2, L3-hot).
// PASS==2: l = a_r + p.o1; writes final output.
template <int PASS>
__global__ __launch_bounds__(256) void routing(const __hip_bfloat16* __restrict__ priors,
                                               float* __restrict__ Abuf,
                                               const float* __restrict__ o_prev,
                                               float* __restrict__ o_out) {
  __shared__ float o_lds[64];
  __shared__ float red_num[4][8][8];
  __shared__ float red_den[4];
  const int kb = blockIdx.x;
  const int tid = threadIdx.x, w = tid >> 6, lane = tid & 63;
  const int g = lane >> 3, sl = lane & 7;
  const int rsub = w * 8 + g;
  const __hip_bfloat16* pbase = priors + (size_t)kb * (NR * NO);
  float* ab = Abuf + (size_t)kb * NR;

  if (PASS == 1) {
    // phase A: column-sum over r -> mean -> squash -> o0
    float sum[8];
#pragma unroll
    for (int j = 0; j < 8; ++j) sum[j] = 0.f;
    for (int it = 0; it < NR / 32; ++it) {
      const int r = it * 32 + rsub;
      uint4 pv = *(const uint4*)(pbase + (size_t)r * NO + sl * 8);
      sum[0] += __builtin_bit_cast(float, pv.x << 16);
      sum[1] += __builtin_bit_cast(float, pv.x & 0xffff0000u);
      sum[2] += __builtin_bit_cast(float, pv.y << 16);
      sum[3] += __builtin_bit_cast(float, pv.y & 0xffff0000u);
      sum[4] += __builtin_bit_cast(float, pv.z << 16);
      sum[5] += __builtin_bit_cast(float, pv.z & 0xffff0000u);
      sum[6] += __builtin_bit_cast(float, pv.w << 16);
      sum[7] += __builtin_bit_cast(float, pv.w & 0xffff0000u);
    }
#pragma unroll
    for (int m = 8; m < 64; m <<= 1)
#pragma unroll
      for (int j = 0; j < 8; ++j) sum[j] += __shfl_xor(sum[j], m, 64);
    if (lane < 8) {
#pragma unroll
      for (int j = 0; j < 8; ++j) red_num[w][lane][j] = sum[j];
    }
    __syncthreads();
    if (tid < 64) {
      const int s_ = tid >> 3, j_ = tid & 7;
      float sv = (red_num[0][s_][j_] + red_num[1][s_][j_] +
                  red_num[2][s_][j_] + red_num[3][s_][j_]) * (1.f / (float)NR);
      float sq = sv * sv;
#pragma unroll
      for (int m = 1; m < 64; m <<= 1) sq += __shfl_xor(sq, m, 64);
      o_lds[tid] = (sq / (1.f + sq)) * rsqrtf(sq) * sv;  // squash
    }
    __syncthreads();
  } else {
    if (tid < 64) o_lds[tid] = o_prev[kb * 64 + tid];
    __syncthreads();
  }

  float os[8];
#pragma unroll
  for (int j = 0; j < 8; ++j) os[j] = o_lds[sl * 8 + j];

  float num[8];
#pragma unroll
  for (int j = 0; j < 8; ++j) num[j] = 0.f;
  float den = 0.f;

  for (int it = 0; it < NR / 32; ++it) {
    const int r = it * 32 + rsub;
    uint4 pv = *(const uint4*)(pbase + (size_t)r * NO + sl * 8);
    float f[8];
    f[0] = __builtin_bit_cast(float, pv.x << 16);
    f[1] = __builtin_bit_cast(float, pv.x & 0xffff0000u);
    f[2] = __builtin_bit_cast(float, pv.y << 16);
    f[3] = __builtin_bit_cast(float, pv.y & 0xffff0000u);
    f[4] = __builtin_bit_cast(float, pv.z << 16);
    f[5] = __builtin_bit_cast(float, pv.z & 0xffff0000u);
    f[6] = __builtin_bit_cast(float, pv.w << 16);
    f[7] = __builtin_bit_cast(float, pv.w & 0xffff0000u);

    float d = 0.f;
#pragma unroll
    for (int j = 0; j < 8; ++j) d = fmaf(f[j], os[j], d);
#pragma unroll
    for (int m = 1; m < 8; m <<= 1) d += __shfl_xor(d, m, 64);  // dot over the 8-lane group

    float lg;
    if (PASS == 1) {
      lg = d;
      if (sl == 0) ab[r] = d;
    } else {
      lg = d + ab[r];
    }
    float e = __expf(lg);  // |lg| << 1, no max-subtraction needed
    den += e;
#pragma unroll
    for (int j = 0; j < 8; ++j) num[j] = fmaf(e, f[j], num[j]);
  }

#pragma unroll
  for (int m = 8; m < 64; m <<= 1) {
    den += __shfl_xor(den, m, 64);
#pragma unroll
    for (int j = 0; j < 8; ++j) num[j] += __shfl_xor(num[j], m, 64);
  }
  if (lane < 8) {
#pragma unroll
    for (int j = 0; j < 8; ++j) red_num[w][lane][j] = num[j];
    if (lane == 0) red_den[w] = den;
  }
  __syncthreads();

  if (tid < 64) {
    const int s_ = tid >> 3, j_ = tid & 7;
    float nm = red_num[0][s_][j_] + red_num[1][s_][j_] + red_num[2][s_][j_] + red_num[3][s_][j_];
    float dn = red_den[0] + red_den[1] + red_den[2] + red_den[3];
    float sv = nm / dn;
    float sq = sv * sv;
#pragma unroll
    for (int m = 1; m < 64; m <<= 1) sq += __shfl_xor(sq, m, 64);
    float ov = (sq / (1.f + sq)) * rsqrtf(sq) * sv;
    o_out[kb * 64 + tid] = ov;
  }
}

extern "C" void kernel_launch(void* const* d_in, const int* in_sizes, int n_in,
                              void* d_out, int out_size, void* d_ws, size_t ws_size,
                              hipStream_t stream) {
  const float* x = (const float*)d_in[0];          // [B][R][CIN]
  const float* W = (const float*)d_in[1];          // [K][R][CIN][COUT]
  float* out = (float*)d_out;                      // [K][B][COUT]
  char* ws = (char*)d_ws;

  size_t off = 0;
  float* xT = (float*)(ws + off);                  off += (size_t)NR * NC * NB * 4;        // 16 MB
  __hip_bfloat16* priors = (__hip_bfloat16*)(ws + off); off += (size_t)NK * NB * NR * NO * 2; // 128 MB
  float* o1 = (float*)(ws + off);                  off += (size_t)NK * NB * NO * 4;        // 128 KB
  float* Abuf = (float*)(ws + off);                off += (size_t)NK * NB * NR * 4;        // 4 MB

  transpose_x<<<NR, 256, 0, stream>>>(x, xT);
  priors_gemm<<<(NR / 4) * NK, 256, 0, stream>>>(xT, W, priors);
  routing<1><<<NK * NB, 256, 0, stream>>>(priors, Abuf, nullptr, o1);
  routing<2><<<NK * NB, 256, 0, stream>>>(priors, Abuf, o1, out);
}

// Round 7
// 255.919 us; speedup vs baseline: 39.6923x; 39.6923x over previous
//
#include <hip/hip_runtime.h>
#include <hip/hip_bf16.h>
#include <stdint.h>

#define NB 32
#define NR 2048
#define NC 64
#define NO 64
#define NK 16
#define CHC 8                 // c's per chunk
#define NCHUNK (NC / CHC)     // 8 chunks

__device__ __forceinline__ uint32_t f2bf(float f) {
  uint32_t u = __builtin_bit_cast(uint32_t, f);
  return (u + 0x7fffu + ((u >> 16) & 1u)) >> 16;  // RNE
}
__device__ __forceinline__ uint32_t packbf2(float lo, float hi) {
  return f2bf(lo) | (f2bf(hi) << 16);
}

__device__ __forceinline__ void gload_lds16(const float* g, float* l) {
  __builtin_amdgcn_global_load_lds(
      (const __attribute__((address_space(1))) void*)g,
      (__attribute__((address_space(3))) void*)l, 16, 0, 0);
}

// x[b][r][c] -> xT[r][c][b]
__global__ __launch_bounds__(256) void transpose_x(const float* __restrict__ x,
                                                   float* __restrict__ xT) {
  __shared__ float tile[32][65];
  const int r = blockIdx.x, t = threadIdx.x;
  {
    const int b = t >> 3, c0 = (t & 7) << 3;
    const float* xp = x + ((size_t)b * NR + r) * NC + c0;
    float4 v0 = *(const float4*)xp;
    float4 v1 = *(const float4*)(xp + 4);
    tile[b][c0 + 0] = v0.x; tile[b][c0 + 1] = v0.y; tile[b][c0 + 2] = v0.z; tile[b][c0 + 3] = v0.w;
    tile[b][c0 + 4] = v1.x; tile[b][c0 + 5] = v1.y; tile[b][c0 + 6] = v1.z; tile[b][c0 + 7] = v1.w;
  }
  __syncthreads();
  {
    const int c = t >> 2, b0 = (t & 3) << 3;
    float4 w0 = make_float4(tile[b0 + 0][c], tile[b0 + 1][c], tile[b0 + 2][c], tile[b0 + 3][c]);
    float4 w1 = make_float4(tile[b0 + 4][c], tile[b0 + 5][c], tile[b0 + 6][c], tile[b0 + 7][c]);
    float* op = xT + ((size_t)r * NC + c) * NB + b0;
    *(float4*)op = w0;
    *(float4*)(op + 4) = w1;
  }
}

// R4-best structure, ONE change: priors layout [k][r][b][o] so each wave's
// 4 store instructions densely fill one 4KB r-slab (was: 32 x 128B segments
// scattered at 256KB stride -> poor DRAM/L2-writeback locality, WRITE 237MB).
// launch_bounds(256,3): R6 proved higher min-occupancy requests spill acc
// (VGPR 40, 32GB scratch traffic). Natural allocation (VGPR ~84) already
// permits up to 6 blocks/CU.
__global__ __launch_bounds__(256, 3) void priors_gemm(const float* __restrict__ xT,
                                                      const float* __restrict__ W,
                                                      __hip_bfloat16* __restrict__ priors) {
  __shared__ float ldsW[2][4][CHC][64];  // [buf][r'][c][o]  2 x 8KB
  __shared__ float ldsX[2][4][CHC][32];  // [buf][r'][c][b]  2 x 4KB
  const int w = threadIdx.x >> 6, lane = threadIdx.x & 63;
  const int bg = lane >> 3, og = lane & 7;
  const int k = blockIdx.x & 15;             // 16 k's of one rquad adjacent -> xT/W L3-hot
  const int rbase = (blockIdx.x >> 4) * 4;
  const int r = rbase + w;

  // W staging: instr i covers row rbase + (w>>1) + i*2, cols [c0+(w&1)*4, +4) x 64 o.
  const float* wsrc = W + ((size_t)(k * NR + rbase + (w >> 1))) * (NC * NO)
                        + (w & 1) * 256 + lane * 4;
  // x staging: wave w stages its own row r, [8 c][32 b] contiguous.
  const float* xsrc = xT + ((size_t)r * NC) * NB + lane * 4;

  float acc[4][8] = {};

  auto stage = [&](int t, int buf) {
    const int c0 = t * CHC;
    float* dw = &ldsW[buf][0][0][0] + w * 256;
    gload_lds16(wsrc + c0 * 64, dw);
    gload_lds16(wsrc + (size_t)2 * (NC * NO) + c0 * 64, dw + 1024);
    gload_lds16(xsrc + c0 * 32, &ldsX[buf][0][0][0] + w * 256);
  };

  auto compute = [&](int buf) {
#pragma unroll
    for (int c = 0; c < CHC; ++c) {
      float4 xv = *(const float4*)&ldsX[buf][w][c][bg * 4];
      float4 wa = *(const float4*)&ldsW[buf][w][c][og * 8];
      float4 wb = *(const float4*)&ldsW[buf][w][c][og * 8 + 4];
      float xr[4] = {xv.x, xv.y, xv.z, xv.w};
      float wr[8] = {wa.x, wa.y, wa.z, wa.w, wb.x, wb.y, wb.z, wb.w};
#pragma unroll
      for (int a = 0; a < 4; ++a)
#pragma unroll
        for (int b = 0; b < 8; ++b) acc[a][b] = fmaf(xr[a], wr[b], acc[a][b]);
    }
  };

  stage(0, 0);
  __syncthreads();
#pragma unroll
  for (int t = 0; t < NCHUNK; ++t) {
    if (t + 1 < NCHUNK) stage(t + 1, (t + 1) & 1);  // prefetch next chunk
    compute(t & 1);                                  // ds_read + FMA current
    __syncthreads();                                 // drain prefetch, swap
  }

  // Dense 4KB r-slab write: priors[k][r][b][o], instr i covers b = bg*4+i
  // for bg 0..7 -> 8 x 128B at 512B stride; 4 instrs fill [r][32][64].
#pragma unroll
  for (int i = 0; i < 4; ++i) {
    uint4 uv;
    uv.x = packbf2(acc[i][0], acc[i][1]);
    uv.y = packbf2(acc[i][2], acc[i][3]);
    uv.z = packbf2(acc[i][4], acc[i][5]);
    uv.w = packbf2(acc[i][6], acc[i][7]);
    __hip_bfloat16* pp = priors + ((size_t)(k * NR + r) * NB + bg * 4 + i) * NO + og * 8;
    *(uint4*)pp = uv;
  }
}

// Routing pass. Block per kb (k = kb>>5, b = kb&31). Lane: g = lane/8, sl = lane%8.
// priors layout [k][r][b][o]: read addr = ((r*NB + b)*NO + sl*8), 128B per r,
// 4KB stride -> served by L2/L3 (priors = 128MB, L3-resident).
// PASS==1: phase A computes o0 = squash(mean_r p) in-block (priors read #1);
//          phase B: l = a_r = p.o0, stores a_r, writes o1 (priors read #2, L3-hot).
// PASS==2: l = a_r + p.o1; writes final output.
template <int PASS>
__global__ __launch_bounds__(256) void routing(const __hip_bfloat16* __restrict__ priors,
                                               float* __restrict__ Abuf,
                                               const float* __restrict__ o_prev,
                                               float* __restrict__ o_out) {
  __shared__ float o_lds[64];
  __shared__ float red_num[4][8][8];
  __shared__ float red_den[4];
  const int kb = blockIdx.x;
  const int k = kb >> 5, b = kb & 31;
  const int tid = threadIdx.x, w = tid >> 6, lane = tid & 63;
  const int g = lane >> 3, sl = lane & 7;
  const int rsub = w * 8 + g;
  const __hip_bfloat16* pbase = priors + (size_t)k * NR * NB * NO + (size_t)b * NO;
  float* ab = Abuf + (size_t)kb * NR;

  if (PASS == 1) {
    // phase A: column-sum over r -> mean -> squash -> o0
    float sum[8];
#pragma unroll
    for (int j = 0; j < 8; ++j) sum[j] = 0.f;
    for (int it = 0; it < NR / 32; ++it) {
      const int r = it * 32 + rsub;
      uint4 pv = *(const uint4*)(pbase + (size_t)r * (NB * NO) + sl * 8);
      sum[0] += __builtin_bit_cast(float, pv.x << 16);
      sum[1] += __builtin_bit_cast(float, pv.x & 0xffff0000u);
      sum[2] += __builtin_bit_cast(float, pv.y << 16);
      sum[3] += __builtin_bit_cast(float, pv.y & 0xffff0000u);
      sum[4] += __builtin_bit_cast(float, pv.z << 16);
      sum[5] += __builtin_bit_cast(float, pv.z & 0xffff0000u);
      sum[6] += __builtin_bit_cast(float, pv.w << 16);
      sum[7] += __builtin_bit_cast(float, pv.w & 0xffff0000u);
    }
#pragma unroll
    for (int m = 8; m < 64; m <<= 1)
#pragma unroll
      for (int j = 0; j < 8; ++j) sum[j] += __shfl_xor(sum[j], m, 64);
    if (lane < 8) {
#pragma unroll
      for (int j = 0; j < 8; ++j) red_num[w][lane][j] = sum[j];
    }
    __syncthreads();
    if (tid < 64) {
      const int s_ = tid >> 3, j_ = tid & 7;
      float sv = (red_num[0][s_][j_] + red_num[1][s_][j_] +
                  red_num[2][s_][j_] + red_num[3][s_][j_]) * (1.f / (float)NR);
      float sq = sv * sv;
#pragma unroll
      for (int m = 1; m < 64; m <<= 1) sq += __shfl_xor(sq, m, 64);
      o_lds[tid] = (sq / (1.f + sq)) * rsqrtf(sq) * sv;  // squash
    }
    __syncthreads();
  } else {
    if (tid < 64) o_lds[tid] = o_prev[kb * 64 + tid];
    __syncthreads();
  }

  float os[8];
#pragma unroll
  for (int j = 0; j < 8; ++j) os[j] = o_lds[sl * 8 + j];

  float num[8];
#pragma unroll
  for (int j = 0; j < 8; ++j) num[j] = 0.f;
  float den = 0.f;

  for (int it = 0; it < NR / 32; ++it) {
    const int r = it * 32 + rsub;
    uint4 pv = *(const uint4*)(pbase + (size_t)r * (NB * NO) + sl * 8);
    float f[8];
    f[0] = __builtin_bit_cast(float, pv.x << 16);
    f[1] = __builtin_bit_cast(float, pv.x & 0xffff0000u);
    f[2] = __builtin_bit_cast(float, pv.y << 16);
    f[3] = __builtin_bit_cast(float, pv.y & 0xffff0000u);
    f[4] = __builtin_bit_cast(float, pv.z << 16);
    f[5] = __builtin_bit_cast(float, pv.z & 0xffff0000u);
    f[6] = __builtin_bit_cast(float, pv.w << 16);
    f[7] = __builtin_bit_cast(float, pv.w & 0xffff0000u);

    float d = 0.f;
#pragma unroll
    for (int j = 0; j < 8; ++j) d = fmaf(f[j], os[j], d);
#pragma unroll
    for (int m = 1; m < 8; m <<= 1) d += __shfl_xor(d, m, 64);  // dot over the 8-lane group

    float lg;
    if (PASS == 1) {
      lg = d;
      if (sl == 0) ab[r] = d;
    } else {
      lg = d + ab[r];
    }
    float e = __expf(lg);  // |lg| << 1, no max-subtraction needed
    den += e;
#pragma unroll
    for (int j = 0; j < 8; ++j) num[j] = fmaf(e, f[j], num[j]);
  }

#pragma unroll
  for (int m = 8; m < 64; m <<= 1) {
    den += __shfl_xor(den, m, 64);
#pragma unroll
    for (int j = 0; j < 8; ++j) num[j] += __shfl_xor(num[j], m, 64);
  }
  if (lane < 8) {
#pragma unroll
    for (int j = 0; j < 8; ++j) red_num[w][lane][j] = num[j];
    if (lane == 0) red_den[w] = den;
  }
  __syncthreads();

  if (tid < 64) {
    const int s_ = tid >> 3, j_ = tid & 7;
    float nm = red_num[0][s_][j_] + red_num[1][s_][j_] + red_num[2][s_][j_] + red_num[3][s_][j_];
    float dn = red_den[0] + red_den[1] + red_den[2] + red_den[3];
    float sv = nm / dn;
    float sq = sv * sv;
#pragma unroll
    for (int m = 1; m < 64; m <<= 1) sq += __shfl_xor(sq, m, 64);
    float ov = (sq / (1.f + sq)) * rsqrtf(sq) * sv;
    o_out[kb * 64 + tid] = ov;
  }
}

extern "C" void kernel_launch(void* const* d_in, const int* in_sizes, int n_in,
                              void* d_out, int out_size, void* d_ws, size_t ws_size,
                              hipStream_t stream) {
  const float* x = (const float*)d_in[0];          // [B][R][CIN]
  const float* W = (const float*)d_in[1];          // [K][R][CIN][COUT]
  float* out = (float*)d_out;                      // [K][B][COUT]
  char* ws = (char*)d_ws;

  size_t off = 0;
  float* xT = (float*)(ws + off);                  off += (size_t)NR * NC * NB * 4;        // 16 MB
  __hip_bfloat16* priors = (__hip_bfloat16*)(ws + off); off += (size_t)NK * NB * NR * NO * 2; // 128 MB
  float* o1 = (float*)(ws + off);                  off += (size_t)NK * NB * NO * 4;        // 128 KB
  float* Abuf = (float*)(ws + off);                off += (size_t)NK * NB * NR * 4;        // 4 MB

  transpose_x<<<NR, 256, 0, stream>>>(x, xT);
  priors_gemm<<<(NR / 4) * NK, 256, 0, stream>>>(xT, W, priors);
  routing<1><<<NK * NB, 256, 0, stream>>>(priors, Abuf, nullptr, o1);
  routing<2><<<NK * NB, 256, 0, stream>>>(priors, Abuf, o1, out);
}

// Round 8
// 255.088 us; speedup vs baseline: 39.8216x; 1.0033x over previous
//
#include <hip/hip_runtime.h>
#include <hip/hip_bf16.h>
#include <stdint.h>

#define NB 32
#define NR 2048
#define NC 64
#define NO 64
#define NK 16
#define CHC 8                 // c's per chunk
#define NCHUNK (NC / CHC)     // 8 chunks

__device__ __forceinline__ uint32_t f2bf(float f) {
  uint32_t u = __builtin_bit_cast(uint32_t, f);
  return (u + 0x7fffu + ((u >> 16) & 1u)) >> 16;  // RNE
}
__device__ __forceinline__ uint32_t packbf2(float lo, float hi) {
  return f2bf(lo) | (f2bf(hi) << 16);
}

__device__ __forceinline__ void gload_lds16(const float* g, float* l) {
  __builtin_amdgcn_global_load_lds(
      (const __attribute__((address_space(1))) void*)g,
      (__attribute__((address_space(3))) void*)l, 16, 0, 0);
}

// x[b][r][c] -> xT[r][c][q] with PERMUTED b: position q holds b(q) = (q&3)*8 + (q>>2).
// So a float4 at q = bg*4.. holds b = {bg, 8+bg, 16+bg, 24+bg} -> the GEMM's
// store instr a (b = a*8+bg) is 1KB-contiguous across the wave.
__global__ __launch_bounds__(256) void transpose_x(const float* __restrict__ x,
                                                   float* __restrict__ xT) {
  __shared__ float tile[32][65];
  const int r = blockIdx.x, t = threadIdx.x;
  {
    const int b = t >> 3, c0 = (t & 7) << 3;
    const float* xp = x + ((size_t)b * NR + r) * NC + c0;
    float4 v0 = *(const float4*)xp;
    float4 v1 = *(const float4*)(xp + 4);
    tile[b][c0 + 0] = v0.x; tile[b][c0 + 1] = v0.y; tile[b][c0 + 2] = v0.z; tile[b][c0 + 3] = v0.w;
    tile[b][c0 + 4] = v1.x; tile[b][c0 + 5] = v1.y; tile[b][c0 + 6] = v1.z; tile[b][c0 + 7] = v1.w;
  }
  __syncthreads();
  {
    const int c = t >> 2, q0 = (t & 3) << 3;
    float v[8];
#pragma unroll
    for (int i = 0; i < 8; ++i) {
      const int q = q0 + i;
      v[i] = tile[(q & 3) * 8 + (q >> 2)][c];  // b(q)
    }
    float* op = xT + ((size_t)r * NC + c) * NB + q0;
    *(float4*)op = make_float4(v[0], v[1], v[2], v[3]);
    *(float4*)(op + 4) = make_float4(v[4], v[5], v[6], v[7]);
  }
}

// R7 structure, ONE change: with the permuted xT, acc[a][*] now corresponds to
// b = a*8 + bg, so store instr a writes priors[k][r][a*8+bg][og*8..]:
// og-lanes give 128B, bg-lanes give 8 consecutive b's -> 1KB CONTIGUOUS per
// store instr, 4KB contiguous per wave. Kills the 128B-fragment partial-line
// writebacks (WRITE_SIZE 237MB ~= 1.85x logical 128MB -> DRAM RMW throttle).
__global__ __launch_bounds__(256, 3) void priors_gemm(const float* __restrict__ xT,
                                                      const float* __restrict__ W,
                                                      __hip_bfloat16* __restrict__ priors) {
  __shared__ float ldsW[2][4][CHC][64];  // [buf][r'][c][o]  2 x 8KB
  __shared__ float ldsX[2][4][CHC][32];  // [buf][r'][c][q]  2 x 4KB
  const int w = threadIdx.x >> 6, lane = threadIdx.x & 63;
  const int bg = lane >> 3, og = lane & 7;
  const int k = blockIdx.x & 15;             // 16 k's of one rquad adjacent -> xT/W L3-hot
  const int rbase = (blockIdx.x >> 4) * 4;
  const int r = rbase + w;

  // W staging: instr i covers row rbase + (w>>1) + i*2, cols [c0+(w&1)*4, +4) x 64 o.
  const float* wsrc = W + ((size_t)(k * NR + rbase + (w >> 1))) * (NC * NO)
                        + (w & 1) * 256 + lane * 4;
  // x staging: wave w stages its own row r, [8 c][32 q] contiguous.
  const float* xsrc = xT + ((size_t)r * NC) * NB + lane * 4;

  float acc[4][8] = {};

  auto stage = [&](int t, int buf) {
    const int c0 = t * CHC;
    float* dw = &ldsW[buf][0][0][0] + w * 256;
    gload_lds16(wsrc + c0 * 64, dw);
    gload_lds16(wsrc + (size_t)2 * (NC * NO) + c0 * 64, dw + 1024);
    gload_lds16(xsrc + c0 * 32, &ldsX[buf][0][0][0] + w * 256);
  };

  auto compute = [&](int buf) {
#pragma unroll
    for (int c = 0; c < CHC; ++c) {
      float4 xv = *(const float4*)&ldsX[buf][w][c][bg * 4];
      float4 wa = *(const float4*)&ldsW[buf][w][c][og * 8];
      float4 wb = *(const float4*)&ldsW[buf][w][c][og * 8 + 4];
      float xr[4] = {xv.x, xv.y, xv.z, xv.w};
      float wr[8] = {wa.x, wa.y, wa.z, wa.w, wb.x, wb.y, wb.z, wb.w};
#pragma unroll
      for (int a = 0; a < 4; ++a)
#pragma unroll
        for (int b = 0; b < 8; ++b) acc[a][b] = fmaf(xr[a], wr[b], acc[a][b]);
    }
  };

  stage(0, 0);
  __syncthreads();
#pragma unroll
  for (int t = 0; t < NCHUNK; ++t) {
    if (t + 1 < NCHUNK) stage(t + 1, (t + 1) & 1);  // prefetch next chunk
    compute(t & 1);                                  // ds_read + FMA current
    __syncthreads();                                 // drain prefetch, swap
  }

  // acc[a][*] is b = a*8 + bg (permuted xT). Store instr a: og-lanes 128B x
  // bg-lanes 8 consecutive b's = 1KB contiguous; 4 instrs = dense 4KB r-slab.
#pragma unroll
  for (int a = 0; a < 4; ++a) {
    uint4 uv;
    uv.x = packbf2(acc[a][0], acc[a][1]);
    uv.y = packbf2(acc[a][2], acc[a][3]);
    uv.z = packbf2(acc[a][4], acc[a][5]);
    uv.w = packbf2(acc[a][6], acc[a][7]);
    __hip_bfloat16* pp = priors + ((size_t)(k * NR + r) * NB + a * 8 + bg) * NO + og * 8;
    *(uint4*)pp = uv;
  }
}

// Routing pass. Block per kb (k = kb>>5, b = kb&31). Lane: g = lane/8, sl = lane%8.
// priors layout [k][r][b][o] (natural b): read addr = ((r*NB + b)*NO + sl*8),
// 128B per r, 4KB stride -> served by L2/L3 (priors = 128MB, L3-resident).
// PASS==1: phase A computes o0 = squash(mean_r p) in-block (priors read #1);
//          phase B: l = a_r = p.o0, stores a_r, writes o1 (priors read #2, L3-hot).
// PASS==2: l = a_r + p.o1; writes final output.
template <int PASS>
__global__ __launch_bounds__(256) void routing(const __hip_bfloat16* __restrict__ priors,
                                               float* __restrict__ Abuf,
                                               const float* __restrict__ o_prev,
                                               float* __restrict__ o_out) {
  __shared__ float o_lds[64];
  __shared__ float red_num[4][8][8];
  __shared__ float red_den[4];
  const int kb = blockIdx.x;
  const int k = kb >> 5, b = kb & 31;
  const int tid = threadIdx.x, w = tid >> 6, lane = tid & 63;
  const int g = lane >> 3, sl = lane & 7;
  const int rsub = w * 8 + g;
  const __hip_bfloat16* pbase = priors + (size_t)k * NR * NB * NO + (size_t)b * NO;
  float* ab = Abuf + (size_t)kb * NR;

  if (PASS == 1) {
    // phase A: column-sum over r -> mean -> squash -> o0
    float sum[8];
#pragma unroll
    for (int j = 0; j < 8; ++j) sum[j] = 0.f;
    for (int it = 0; it < NR / 32; ++it) {
      const int r = it * 32 + rsub;
      uint4 pv = *(const uint4*)(pbase + (size_t)r * (NB * NO) + sl * 8);
      sum[0] += __builtin_bit_cast(float, pv.x << 16);
      sum[1] += __builtin_bit_cast(float, pv.x & 0xffff0000u);
      sum[2] += __builtin_bit_cast(float, pv.y << 16);
      sum[3] += __builtin_bit_cast(float, pv.y & 0xffff0000u);
      sum[4] += __builtin_bit_cast(float, pv.z << 16);
      sum[5] += __builtin_bit_cast(float, pv.z & 0xffff0000u);
      sum[6] += __builtin_bit_cast(float, pv.w << 16);
      sum[7] += __builtin_bit_cast(float, pv.w & 0xffff0000u);
    }
#pragma unroll
    for (int m = 8; m < 64; m <<= 1)
#pragma unroll
      for (int j = 0; j < 8; ++j) sum[j] += __shfl_xor(sum[j], m, 64);
    if (lane < 8) {
#pragma unroll
      for (int j = 0; j < 8; ++j) red_num[w][lane][j] = sum[j];
    }
    __syncthreads();
    if (tid < 64) {
      const int s_ = tid >> 3, j_ = tid & 7;
      float sv = (red_num[0][s_][j_] + red_num[1][s_][j_] +
                  red_num[2][s_][j_] + red_num[3][s_][j_]) * (1.f / (float)NR);
      float sq = sv * sv;
#pragma unroll
      for (int m = 1; m < 64; m <<= 1) sq += __shfl_xor(sq, m, 64);
      o_lds[tid] = (sq / (1.f + sq)) * rsqrtf(sq) * sv;  // squash
    }
    __syncthreads();
  } else {
    if (tid < 64) o_lds[tid] = o_prev[kb * 64 + tid];
    __syncthreads();
  }

  float os[8];
#pragma unroll
  for (int j = 0; j < 8; ++j) os[j] = o_lds[sl * 8 + j];

  float num[8];
#pragma unroll
  for (int j = 0; j < 8; ++j) num[j] = 0.f;
  float den = 0.f;

  for (int it = 0; it < NR / 32; ++it) {
    const int r = it * 32 + rsub;
    uint4 pv = *(const uint4*)(pbase + (size_t)r * (NB * NO) + sl * 8);
    float f[8];
    f[0] = __builtin_bit_cast(float, pv.x << 16);
    f[1] = __builtin_bit_cast(float, pv.x & 0xffff0000u);
    f[2] = __builtin_bit_cast(float, pv.y << 16);
    f[3] = __builtin_bit_cast(float, pv.y & 0xffff0000u);
    f[4] = __builtin_bit_cast(float, pv.z << 16);
    f[5] = __builtin_bit_cast(float, pv.z & 0xffff0000u);
    f[6] = __builtin_bit_cast(float, pv.w << 16);
    f[7] = __builtin_bit_cast(float, pv.w & 0xffff0000u);

    float d = 0.f;
#pragma unroll
    for (int j = 0; j < 8; ++j) d = fmaf(f[j], os[j], d);
#pragma unroll
    for (int m = 1; m < 8; m <<= 1) d += __shfl_xor(d, m, 64);  // dot over the 8-lane group

    float lg;
    if (PASS == 1) {
      lg = d;
      if (sl == 0) ab[r] = d;
    } else {
      lg = d + ab[r];
    }
    float e = __expf(lg);  // |lg| << 1, no max-subtraction needed
    den += e;
#pragma unroll
    for (int j = 0; j < 8; ++j) num[j] = fmaf(e, f[j], num[j]);
  }

#pragma unroll
  for (int m = 8; m < 64; m <<= 1) {
    den += __shfl_xor(den, m, 64);
#pragma unroll
    for (int j = 0; j < 8; ++j) num[j] += __shfl_xor(num[j], m, 64);
  }
  if (lane < 8) {
#pragma unroll
    for (int j = 0; j < 8; ++j) red_num[w][lane][j] = num[j];
    if (lane == 0) red_den[w] = den;
  }
  __syncthreads();

  if (tid < 64) {
    const int s_ = tid >> 3, j_ = tid & 7;
    float nm = red_num[0][s_][j_] + red_num[1][s_][j_] + red_num[2][s_][j_] + red_num[3][s_][j_];
    float dn = red_den[0] + red_den[1] + red_den[2] + red_den[3];
    float sv = nm / dn;
    float sq = sv * sv;
#pragma unroll
    for (int m = 1; m < 64; m <<= 1) sq += __shfl_xor(sq, m, 64);
    float ov = (sq / (1.f + sq)) * rsqrtf(sq) * sv;
    o_out[kb * 64 + tid] = ov;
  }
}

extern "C" void kernel_launch(void* const* d_in, const int* in_sizes, int n_in,
                              void* d_out, int out_size, void* d_ws, size_t ws_size,
                              hipStream_t stream) {
  const float* x = (const float*)d_in[0];          // [B][R][CIN]
  const float* W = (const float*)d_in[1];          // [K][R][CIN][COUT]
  float* out = (float*)d_out;                      // [K][B][COUT]
  char* ws = (char*)d_ws;

  size_t off = 0;
  float* xT = (float*)(ws + off);                  off += (size_t)NR * NC * NB * 4;        // 16 MB
  __hip_bfloat16* priors = (__hip_bfloat16*)(ws + off); off += (size_t)NK * NB * NR * NO * 2; // 128 MB
  float* o1 = (float*)(ws + off);                  off += (size_t)NK * NB * NO * 4;        // 128 KB
  float* Abuf = (float*)(ws + off);                off += (size_t)NK * NB * NR * 4;        // 4 MB

  transpose_x<<<NR, 256, 0, stream>>>(x, xT);
  priors_gemm<<<(NR / 4) * NK, 256, 0, stream>>>(xT, W, priors);
  routing<1><<<NK * NB, 256, 0, stream>>>(priors, Abuf, nullptr, o1);
  routing<2><<<NK * NB, 256, 0, stream>>>(priors, Abuf, o1, out);
}